// Round 2
// baseline (836.250 us; speedup 1.0000x reference)
//
#include <hip/hip_runtime.h>
#include <hip/hip_bf16.h>

typedef unsigned short u16;
typedef unsigned int   u32;

#define N_NODES 100000
#define N_EDGES 1600000

__device__ __forceinline__ float bf2f(u16 u) {
    union { u32 i; float f; } c; c.i = ((u32)u) << 16; return c.f;
}
__device__ __forceinline__ u16 f2bf(float f) {
    union { float f; u32 i; } c; c.f = f;
    u32 u = c.i;
    u += 0x7fffu + ((u >> 16) & 1u);   // round-to-nearest-even
    return (u16)(u >> 16);
}

// ---------------- edge dtype probe (int32 vs int64 layout) ----------------
// If edge_index was kept int64, the u32 view is (lo,hi) pairs with hi==0
// (values in [0,1e5)). Probability a genuine int32 stream has u32[1,3,5,7]
// all zero is ~1e-20.
__global__ void k_detect(const u32* __restrict__ ei, int* __restrict__ flag) {
    if (threadIdx.x == 0 && blockIdx.x == 0) {
        u32 h = ei[1] | ei[3] | ei[5] | ei[7];
        *flag = (h == 0u) ? 1 : 0;
    }
}

__device__ __forceinline__ int edge_at(const u32* ei, int f, long pos) {
    return f ? (int)ei[2 * pos] : (int)ei[pos];
}

// ---------------- degree / CSR build ----------------

__global__ void k_degree(const u32* __restrict__ ei, const int* __restrict__ flag,
                         int* __restrict__ deg) {
    int e = blockIdx.x * blockDim.x + threadIdx.x;
    int f = *flag;
    if (e < N_EDGES) {
        int d = edge_at(ei, f, (long)N_EDGES + e);
        atomicAdd(&deg[d], 1);
    }
}

// 49 blocks x 256 threads x 8 elems = 100352 >= 100000
__global__ void k_scan_part(const int* __restrict__ deg, int* __restrict__ rowstart,
                            int* __restrict__ bsums) {
    __shared__ int sh[256];
    const int t = threadIdx.x, b = blockIdx.x;
    const int base = b * 2048 + t * 8;
    int v[8]; int s = 0;
#pragma unroll
    for (int i = 0; i < 8; i++) {
        int idx = base + i;
        v[i] = (idx < N_NODES) ? deg[idx] : 0;
        s += v[i];
    }
    sh[t] = s;
    __syncthreads();
    for (int d = 1; d < 256; d <<= 1) {
        int x = (t >= d) ? sh[t - d] : 0;
        __syncthreads();
        sh[t] += x;
        __syncthreads();
    }
    int acc = sh[t] - s;   // exclusive prefix of this thread's chunk
#pragma unroll
    for (int i = 0; i < 8; i++) {
        int idx = base + i;
        if (idx < N_NODES) rowstart[idx] = acc;
        acc += v[i];
    }
    if (t == 255) bsums[b] = sh[255];
}

__global__ void k_scan_sums(const int* __restrict__ bsums, int* __restrict__ boffs, int nb) {
    if (threadIdx.x == 0 && blockIdx.x == 0) {
        int r = 0;
        for (int i = 0; i < nb; i++) { boffs[i] = r; r += bsums[i]; }
    }
}

__global__ void k_scan_add_dinv(int* __restrict__ rowstart, const int* __restrict__ boffs,
                                const int* __restrict__ deg, float* __restrict__ dinv) {
    int i = blockIdx.x * blockDim.x + threadIdx.x;
    if (i < N_NODES) {
        rowstart[i] += boffs[i >> 11];
        dinv[i] = rsqrtf((float)(deg[i] + 1));   // +1 self-loop
    }
    if (i == 0) rowstart[N_NODES] = N_EDGES;
}

__global__ void k_fill(const u32* __restrict__ ei, const int* __restrict__ flag,
                       const int* __restrict__ rowstart, int* __restrict__ cursor,
                       int* __restrict__ csr) {
    int e = blockIdx.x * blockDim.x + threadIdx.x;
    int f = *flag;
    if (e < N_EDGES) {
        int s = edge_at(ei, f, e);
        int d = edge_at(ei, f, (long)N_EDGES + e);
        int p = rowstart[d] + atomicAdd(&cursor[d], 1);
        csr[p] = s;
    }
}

// ---------------- MFMA GEMM: C[M,NO] = A[M,K] * B[K,NO] ----------------
// A: f32 (AF32=true) or bf16; B: f32 (converted to bf16 in staging); C: bf16.

template <int K, int NO, bool AF32>
__global__ __launch_bounds__(256) void gemm_mfma(const void* __restrict__ Av,
                                                 const float* __restrict__ B,
                                                 u16* __restrict__ C, int M) {
    constexpr int NT = NO / 16;   // col tiles per wave
    constexpr int SA = 40;        // padded LDS stride (elems)
    __shared__ u16 As[64 * SA];
    __shared__ u16 Bs[NO * SA];   // transposed: Bs[n][k]
    typedef __attribute__((ext_vector_type(8))) short v8s;
    typedef __attribute__((ext_vector_type(4))) float v4f;

    const int t = threadIdx.x;
    const int wave = t >> 6, lane = t & 63;
    const int m = lane & 15, quad = lane >> 4;
    const int row0 = blockIdx.x * 64;

    v4f acc[NT];
#pragma unroll
    for (int c = 0; c < NT; c++)
#pragma unroll
        for (int r = 0; r < 4; r++) acc[c][r] = 0.0f;

    const int arow = t >> 2, achk = t & 3;   // 64 rows x (4 chunks of 8 k)
    const long aoff = (long)(row0 + arow) * K;
    const bool arow_ok = (row0 + arow) < M;

    for (int kt = 0; kt < K / 32; ++kt) {
        const int kk0 = kt * 32;
        // ---- stage A tile: 64 rows x 32 k (to bf16) ----
        if (AF32) {
            const float* A = (const float*)Av;
            float4 av0 = make_float4(0.f, 0.f, 0.f, 0.f), av1 = av0;
            if (arow_ok) {
                av0 = *(const float4*)&A[aoff + kk0 + achk * 8];
                av1 = *(const float4*)&A[aoff + kk0 + achk * 8 + 4];
            }
            u32 p0 = (u32)f2bf(av0.x) | ((u32)f2bf(av0.y) << 16);
            u32 p1 = (u32)f2bf(av0.z) | ((u32)f2bf(av0.w) << 16);
            u32 p2 = (u32)f2bf(av1.x) | ((u32)f2bf(av1.y) << 16);
            u32 p3 = (u32)f2bf(av1.z) | ((u32)f2bf(av1.w) << 16);
            *(uint4*)&As[arow * SA + achk * 8] = make_uint4(p0, p1, p2, p3);
        } else {
            const u16* A = (const u16*)Av;
            uint4 av = make_uint4(0u, 0u, 0u, 0u);
            if (arow_ok) av = *(const uint4*)&A[aoff + kk0 + achk * 8];
            *(uint4*)&As[arow * SA + achk * 8] = av;
        }
        // ---- stage B tile transposed: 32 k x NO n (f32 -> bf16) ----
        for (int i = t; i < 32 * (NO / 2); i += 256) {
            int k = i / (NO / 2), n2 = i % (NO / 2);
            float2 d = *(const float2*)&B[(long)(kk0 + k) * NO + n2 * 2];
            Bs[(n2 * 2) * SA + k]     = f2bf(d.x);
            Bs[(n2 * 2 + 1) * SA + k] = f2bf(d.y);
        }
        __syncthreads();
        v8s a = *(const v8s*)&As[(wave * 16 + m) * SA + quad * 8];
#pragma unroll
        for (int c = 0; c < NT; c++) {
            v8s b = *(const v8s*)&Bs[(c * 16 + m) * SA + quad * 8];
            acc[c] = __builtin_amdgcn_mfma_f32_16x16x32_bf16(a, b, acc[c], 0, 0, 0);
        }
        __syncthreads();
    }
    // D layout: col = lane&15, row = quad*4 + r  [m89]
#pragma unroll
    for (int c = 0; c < NT; c++)
#pragma unroll
        for (int r = 0; r < 4; r++) {
            int grow = row0 + wave * 16 + quad * 4 + r;
            if (grow < M) C[(long)grow * NO + c * 16 + m] = f2bf(acc[c][r]);
        }
}

// ---------------- aggregation (gather over CSR), D=128, bf16 out ----------------

__global__ __launch_bounds__(256) void agg128(const u16* __restrict__ h,
                                              const float* __restrict__ dinv,
                                              const int* __restrict__ rowstart,
                                              const int* __restrict__ csr,
                                              const float* __restrict__ bias,
                                              u16* __restrict__ out) {
    const int wave = threadIdx.x >> 6, lane = threadIdx.x & 63;
    const int n = blockIdx.x * 4 + wave;
    const u32* h32 = (const u32*)h;
    float a0 = 0.f, a1 = 0.f;
    const float w0 = dinv[n];
    {
        u32 d = h32[(long)n * 64 + lane];   // self-loop
        float w = w0 * w0;
        a0 += bf2f((u16)(d & 0xffffu)) * w;
        a1 += bf2f((u16)(d >> 16)) * w;
    }
    const int i1 = rowstart[n + 1];
    for (int i = rowstart[n]; i < i1; i++) {
        int s = csr[i];
        float w = dinv[s] * w0;
        u32 d = h32[(long)s * 64 + lane];
        a0 += bf2f((u16)(d & 0xffffu)) * w;
        a1 += bf2f((u16)(d >> 16)) * w;
    }
    float2 bd = ((const float2*)bias)[lane];
    a0 += bd.x;
    a1 += bd.y;
    u32 o = (u32)f2bf(a0) | ((u32)f2bf(a1) << 16);
    ((u32*)out)[(long)n * 64 + lane] = o;
}

// ---------------- aggregation D=64 + bias + relu, f32 out ----------------

__global__ __launch_bounds__(256) void agg64_relu(const u16* __restrict__ h,
                                                  const float* __restrict__ dinv,
                                                  const int* __restrict__ rowstart,
                                                  const int* __restrict__ csr,
                                                  const float* __restrict__ bias,
                                                  float* __restrict__ out) {
    const int wave = threadIdx.x >> 6, lane = threadIdx.x & 63;
    const int n = blockIdx.x * 4 + wave;
    const int half = lane >> 5, l = lane & 31;
    const u32* h32 = (const u32*)h;
    float a0 = 0.f, a1 = 0.f;
    const float w0 = dinv[n];
    if (half == 0) {
        u32 d = h32[(long)n * 32 + l];      // self-loop
        float w = w0 * w0;
        a0 += bf2f((u16)(d & 0xffffu)) * w;
        a1 += bf2f((u16)(d >> 16)) * w;
    }
    const int i1 = rowstart[n + 1];
    for (int i = rowstart[n] + half; i < i1; i += 2) {
        int s = csr[i];
        float w = dinv[s] * w0;
        u32 d = h32[(long)s * 32 + l];
        a0 += bf2f((u16)(d & 0xffffu)) * w;
        a1 += bf2f((u16)(d >> 16)) * w;
    }
    a0 += __shfl_down(a0, 32);
    a1 += __shfl_down(a1, 32);
    if (half == 0) {
        float2 bd = ((const float2*)bias)[l];
        float r0 = fmaxf(a0 + bd.x, 0.f);
        float r1 = fmaxf(a1 + bd.y, 0.f);
        ((float2*)out)[(long)n * 32 + l] = make_float2(r0, r1);
    }
}

// ---------------- host launch ----------------

extern "C" void kernel_launch(void* const* d_in, const int* in_sizes, int n_in,
                              void* d_out, int out_size, void* d_ws, size_t ws_size,
                              hipStream_t stream) {
    const float* x  = (const float*)d_in[0];
    const u32*   ei = (const u32*)d_in[1];
    const float* W1 = (const float*)d_in[2];
    const float* b1 = (const float*)d_in[3];
    const float* W2 = (const float*)d_in[4];
    const float* b2 = (const float*)d_in[5];
    float* out = (float*)d_out;

    char* ws = (char*)d_ws;
    size_t o = 0;
    auto alloc = [&](size_t bytes) -> char* {
        char* p = ws + o;
        o = (o + bytes + 255) & ~(size_t)255;
        return p;
    };
    int*   deg      = (int*)  alloc(N_NODES * 4);
    float* dinv     = (float*)alloc(N_NODES * 4);
    int*   rowstart = (int*)  alloc((N_NODES + 1) * 4);
    int*   cursor   = (int*)  alloc(N_NODES * 4);
    int*   bsums    = (int*)  alloc(64 * 4);
    int*   boffs    = (int*)  alloc(64 * 4);
    int*   eflag    = (int*)  alloc(256);
    int*   csr      = (int*)  alloc((size_t)N_EDGES * 4);
    u16*   h1       = (u16*)  alloc((size_t)N_NODES * 128 * 2);  // also reused as h2
    u16*   g1       = (u16*)  alloc((size_t)N_NODES * 128 * 2);
    u16*   h2       = h1;   // h1 dead after agg128; alias to cap ws at ~59 MB
    (void)ws_size;

    hipMemsetAsync(deg, 0, N_NODES * 4, stream);
    hipMemsetAsync(cursor, 0, N_NODES * 4, stream);

    const int EB = (N_EDGES + 255) / 256;
    const int NB = (N_NODES + 255) / 256;
    const int SCAN_BLKS = (N_NODES + 2047) / 2048;   // 49

    k_detect<<<1, 64, 0, stream>>>(ei, eflag);
    k_degree<<<EB, 256, 0, stream>>>(ei, eflag, deg);
    k_scan_part<<<SCAN_BLKS, 256, 0, stream>>>(deg, rowstart, bsums);
    k_scan_sums<<<1, 64, 0, stream>>>(bsums, boffs, SCAN_BLKS);
    k_scan_add_dinv<<<NB, 256, 0, stream>>>(rowstart, boffs, deg, dinv);
    k_fill<<<EB, 256, 0, stream>>>(ei, eflag, rowstart, cursor, csr);

    const int GEMM_BLKS = (N_NODES + 63) / 64;       // 1563
    gemm_mfma<512, 128, true><<<GEMM_BLKS, 256, 0, stream>>>(x, W1, h1, N_NODES);
    agg128<<<N_NODES / 4, 256, 0, stream>>>(h1, dinv, rowstart, csr, b1, g1);
    gemm_mfma<128, 64, false><<<GEMM_BLKS, 256, 0, stream>>>(g1, W2, h2, N_NODES);
    agg64_relu<<<N_NODES / 4, 256, 0, stream>>>(h2, dinv, rowstart, csr, b2, out);
}

// Round 3
// 711.008 us; speedup vs baseline: 1.1761x; 1.1761x over previous
//
#include <hip/hip_runtime.h>
#include <hip/hip_bf16.h>

typedef unsigned short u16;
typedef unsigned int   u32;

#define N_NODES 100000
#define N_EDGES 1600000

__device__ __forceinline__ float bf2f(u16 u) {
    union { u32 i; float f; } c; c.i = ((u32)u) << 16; return c.f;
}
__device__ __forceinline__ u16 f2bf(float f) {
    union { float f; u32 i; } c; c.f = f;
    u32 u = c.i;
    u += 0x7fffu + ((u >> 16) & 1u);   // RNE
    return (u16)(u >> 16);
}

// ---------------- edge dtype probe (int32 vs int64 layout) ----------------
__global__ void k_detect(const u32* __restrict__ ei, int* __restrict__ flag) {
    if (threadIdx.x == 0 && blockIdx.x == 0) {
        u32 h = ei[1] | ei[3] | ei[5] | ei[7];
        *flag = (h == 0u) ? 1 : 0;
    }
}
__device__ __forceinline__ int edge_at(const u32* ei, int f, long pos) {
    return f ? (int)ei[2 * pos] : (int)ei[pos];
}

// ---------------- degree / CSR build ----------------

__global__ void k_degree(const u32* __restrict__ ei, const int* __restrict__ flag,
                         int* __restrict__ deg) {
    int e = blockIdx.x * blockDim.x + threadIdx.x;
    int f = *flag;
    if (e < N_EDGES) atomicAdd(&deg[edge_at(ei, f, (long)N_EDGES + e)], 1);
}

__global__ void k_scan_part(const int* __restrict__ deg, int* __restrict__ rowstart,
                            int* __restrict__ bsums) {
    __shared__ int sh[256];
    const int t = threadIdx.x, b = blockIdx.x;
    const int base = b * 2048 + t * 8;
    int v[8]; int s = 0;
#pragma unroll
    for (int i = 0; i < 8; i++) {
        int idx = base + i;
        v[i] = (idx < N_NODES) ? deg[idx] : 0;
        s += v[i];
    }
    sh[t] = s;
    __syncthreads();
    for (int d = 1; d < 256; d <<= 1) {
        int x = (t >= d) ? sh[t - d] : 0;
        __syncthreads();
        sh[t] += x;
        __syncthreads();
    }
    int acc = sh[t] - s;
#pragma unroll
    for (int i = 0; i < 8; i++) {
        int idx = base + i;
        if (idx < N_NODES) rowstart[idx] = acc;
        acc += v[i];
    }
    if (t == 255) bsums[b] = sh[255];
}

__global__ void k_scan_sums(const int* __restrict__ bsums, int* __restrict__ boffs, int nb) {
    if (threadIdx.x == 0 && blockIdx.x == 0) {
        int r = 0;
        for (int i = 0; i < nb; i++) { boffs[i] = r; r += bsums[i]; }
    }
}

__global__ void k_scan_add_dinv(int* __restrict__ rowstart, const int* __restrict__ boffs,
                                const int* __restrict__ deg, float* __restrict__ dinv) {
    int i = blockIdx.x * blockDim.x + threadIdx.x;
    if (i < N_NODES) {
        rowstart[i] += boffs[i >> 11];
        dinv[i] = rsqrtf((float)(deg[i] + 1));
    }
    if (i == 0) rowstart[N_NODES] = N_EDGES;
}

__global__ void k_fill(const u32* __restrict__ ei, const int* __restrict__ flag,
                       const int* __restrict__ rowstart, int* __restrict__ cursor,
                       int* __restrict__ csr) {
    int e = blockIdx.x * blockDim.x + threadIdx.x;
    int f = *flag;
    if (e < N_EDGES) {
        int s = edge_at(ei, f, e);
        int d = edge_at(ei, f, (long)N_EDGES + e);
        int p = rowstart[d] + atomicAdd(&cursor[d], 1);
        csr[p] = s;
    }
}

// ---------------- weight precompute: W12 = W1@W2 (f32), c1 = b1@W2 ----------------

__global__ void k_w12(const float* __restrict__ W1, const float* __restrict__ W2,
                      float* __restrict__ W12f) {
    int idx = blockIdx.x * 256 + threadIdx.x;   // 512*64 = 32768
    int k = idx >> 6, n = idx & 63;
    float acc = 0.f;
#pragma unroll 4
    for (int j = 0; j < 128; j++) acc += W1[k * 128 + j] * W2[j * 64 + n];
    W12f[idx] = acc;
}

__global__ void k_c1(const float* __restrict__ b1, const float* __restrict__ W2,
                     float* __restrict__ c1) {
    int n = threadIdx.x;   // 64
    float acc = 0.f;
    for (int j = 0; j < 128; j++) acc += b1[j] * W2[j * 64 + n];
    c1[n] = acc;
}

// fragment-ordered bf16 pack: Bt[(kt*4+c)*64 + lane] holds 8 elems:
//   B[k = kt*32 + (lane>>4)*8 + j][n = c*16 + (lane&15)], j=0..7
__global__ void k_fragB(const float* __restrict__ W12f, u16* __restrict__ Bt) {
    int idx = blockIdx.x * 256 + threadIdx.x;   // 16 blocks -> 4096 threads
    int l = idx & 63, c = (idx >> 6) & 3, kt = idx >> 8;
    int n = c * 16 + (l & 15);
    int k0 = kt * 32 + (l >> 4) * 8;
    u32 p[4];
#pragma unroll
    for (int j = 0; j < 4; j++) {
        u16 a = f2bf(W12f[(k0 + 2 * j) * 64 + n]);
        u16 b = f2bf(W12f[(k0 + 2 * j + 1) * 64 + n]);
        p[j] = (u32)a | ((u32)b << 16);
    }
    *(uint4*)&Bt[(long)idx * 8] = make_uint4(p[0], p[1], p[2], p[3]);
}

// ---------------- GEMM: z[M,64] = bf16(x[M,512]) @ Bt, out bf16 ----------------

__global__ __launch_bounds__(256) void gemm_x(const float* __restrict__ A,
                                              const u16* __restrict__ Bt,
                                              u16* __restrict__ C, int M) {
    constexpr int SA = 40;        // padded LDS stride (u16 elems)
    __shared__ u16 As[128 * SA];  // 10 KB
    typedef __attribute__((ext_vector_type(8))) short v8s;
    typedef __attribute__((ext_vector_type(4))) float v4f;

    const int t = threadIdx.x;
    const int wave = t >> 6, lane = t & 63;
    const int m = lane & 15, quad = lane >> 4;
    const int row0 = blockIdx.x * 128;

    v4f acc[2][4];
#pragma unroll
    for (int i = 0; i < 2; i++)
#pragma unroll
        for (int c = 0; c < 4; c++)
#pragma unroll
            for (int r = 0; r < 4; r++) acc[i][c][r] = 0.0f;

    const int arow = t >> 1, ahalf = t & 1;   // 128 rows x 2 halves of 16 k
    const long aoff = (long)(row0 + arow) * 512;
    const bool arow_ok = (row0 + arow) < M;

    for (int kt = 0; kt < 16; ++kt) {
        const int kk0 = kt * 32 + ahalf * 16;
        float4 f0 = make_float4(0.f, 0.f, 0.f, 0.f), f1 = f0, f2 = f0, f3 = f0;
        if (arow_ok) {
            f0 = *(const float4*)&A[aoff + kk0];
            f1 = *(const float4*)&A[aoff + kk0 + 4];
            f2 = *(const float4*)&A[aoff + kk0 + 8];
            f3 = *(const float4*)&A[aoff + kk0 + 12];
        }
        uint4 w0, w1;
        w0.x = (u32)f2bf(f0.x) | ((u32)f2bf(f0.y) << 16);
        w0.y = (u32)f2bf(f0.z) | ((u32)f2bf(f0.w) << 16);
        w0.z = (u32)f2bf(f1.x) | ((u32)f2bf(f1.y) << 16);
        w0.w = (u32)f2bf(f1.z) | ((u32)f2bf(f1.w) << 16);
        w1.x = (u32)f2bf(f2.x) | ((u32)f2bf(f2.y) << 16);
        w1.y = (u32)f2bf(f2.z) | ((u32)f2bf(f2.w) << 16);
        w1.z = (u32)f2bf(f3.x) | ((u32)f2bf(f3.y) << 16);
        w1.w = (u32)f2bf(f3.z) | ((u32)f2bf(f3.w) << 16);
        *(uint4*)&As[arow * SA + ahalf * 16] = w0;
        *(uint4*)&As[arow * SA + ahalf * 16 + 8] = w1;
        __syncthreads();
        v8s a0 = *(const v8s*)&As[(wave * 32 + m) * SA + quad * 8];
        v8s a1 = *(const v8s*)&As[(wave * 32 + 16 + m) * SA + quad * 8];
#pragma unroll
        for (int c = 0; c < 4; c++) {
            v8s b = *(const v8s*)&Bt[(long)((kt * 4 + c) * 64 + lane) * 8];
            acc[0][c] = __builtin_amdgcn_mfma_f32_16x16x32_bf16(a0, b, acc[0][c], 0, 0, 0);
            acc[1][c] = __builtin_amdgcn_mfma_f32_16x16x32_bf16(a1, b, acc[1][c], 0, 0, 0);
        }
        __syncthreads();
    }
    // D layout: col = lane&15, row = quad*4 + r
#pragma unroll
    for (int i = 0; i < 2; i++)
#pragma unroll
        for (int c = 0; c < 4; c++)
#pragma unroll
            for (int r = 0; r < 4; r++) {
                int grow = row0 + wave * 32 + i * 16 + quad * 4 + r;
                if (grow < M) C[(long)grow * 64 + c * 16 + m] = f2bf(acc[i][c][r]);
            }
}

// ---------------- aggregation pass 1: y = A_hat @ z (bf16 -> bf16) ----------------

__global__ __launch_bounds__(256) void agg_a(const u16* __restrict__ z,
                                             const float* __restrict__ dinv,
                                             const int* __restrict__ rowstart,
                                             const int* __restrict__ csr,
                                             u16* __restrict__ y) {
    const int wave = threadIdx.x >> 6, lane = threadIdx.x & 63;
    const int n = blockIdx.x * 4 + wave;
    const int half = lane >> 5, l = lane & 31;
    const u32* z32 = (const u32*)z;
    float a0 = 0.f, a1 = 0.f;
    const float w0 = dinv[n];
    if (half == 0) {
        u32 d = z32[(long)n * 32 + l];
        float w = w0 * w0;
        a0 += bf2f((u16)(d & 0xffffu)) * w;
        a1 += bf2f((u16)(d >> 16)) * w;
    }
    const int i1 = rowstart[n + 1];
    for (int i = rowstart[n] + half; i < i1; i += 2) {
        int s = csr[i];
        float w = dinv[s] * w0;
        u32 d = z32[(long)s * 32 + l];
        a0 += bf2f((u16)(d & 0xffffu)) * w;
        a1 += bf2f((u16)(d >> 16)) * w;
    }
    a0 += __shfl_down(a0, 32);
    a1 += __shfl_down(a1, 32);
    if (half == 0) {
        u32 o = (u32)f2bf(a0) | ((u32)f2bf(a1) << 16);
        ((u32*)y)[(long)n * 32 + l] = o;
    }
}

// ---------------- aggregation pass 2: out = relu(A_hat @ y + s*c1 + b2), f32 out ----
// s_n = sum of norm over self+edges, accumulated inline (dinv[s] already loaded).

__global__ __launch_bounds__(256) void agg_b(const u16* __restrict__ y,
                                             const float* __restrict__ dinv,
                                             const int* __restrict__ rowstart,
                                             const int* __restrict__ csr,
                                             const float* __restrict__ c1,
                                             const float* __restrict__ b2,
                                             float* __restrict__ out) {
    const int wave = threadIdx.x >> 6, lane = threadIdx.x & 63;
    const int n = blockIdx.x * 4 + wave;
    const int half = lane >> 5, l = lane & 31;
    const u32* y32 = (const u32*)y;
    float a0 = 0.f, a1 = 0.f, sacc = 0.f;
    const float w0 = dinv[n];
    if (half == 0) {
        u32 d = y32[(long)n * 32 + l];
        float w = w0 * w0;
        sacc += w;
        a0 += bf2f((u16)(d & 0xffffu)) * w;
        a1 += bf2f((u16)(d >> 16)) * w;
    }
    const int i1 = rowstart[n + 1];
    for (int i = rowstart[n] + half; i < i1; i += 2) {
        int s = csr[i];
        float w = dinv[s] * w0;
        sacc += w;
        u32 d = y32[(long)s * 32 + l];
        a0 += bf2f((u16)(d & 0xffffu)) * w;
        a1 += bf2f((u16)(d >> 16)) * w;
    }
    a0 += __shfl_down(a0, 32);
    a1 += __shfl_down(a1, 32);
    sacc += __shfl_down(sacc, 32);
    if (half == 0) {
        float2 cv = ((const float2*)c1)[l];
        float2 bv = ((const float2*)b2)[l];
        float r0 = fmaxf(a0 + sacc * cv.x + bv.x, 0.f);
        float r1 = fmaxf(a1 + sacc * cv.y + bv.y, 0.f);
        ((float2*)out)[(long)n * 32 + l] = make_float2(r0, r1);
    }
}

// ---------------- host launch ----------------

extern "C" void kernel_launch(void* const* d_in, const int* in_sizes, int n_in,
                              void* d_out, int out_size, void* d_ws, size_t ws_size,
                              hipStream_t stream) {
    const float* x  = (const float*)d_in[0];
    const u32*   ei = (const u32*)d_in[1];
    const float* W1 = (const float*)d_in[2];
    const float* b1 = (const float*)d_in[3];
    const float* W2 = (const float*)d_in[4];
    const float* b2 = (const float*)d_in[5];
    float* out = (float*)d_out;

    char* ws = (char*)d_ws;
    size_t o = 0;
    auto alloc = [&](size_t bytes) -> char* {
        char* p = ws + o;
        o = (o + bytes + 255) & ~(size_t)255;
        return p;
    };
    int*   deg      = (int*)  alloc(N_NODES * 4);
    float* dinv     = (float*)alloc(N_NODES * 4);
    int*   rowstart = (int*)  alloc((N_NODES + 1) * 4);
    int*   cursor   = (int*)  alloc(N_NODES * 4);
    int*   bsums    = (int*)  alloc(64 * 4);
    int*   boffs    = (int*)  alloc(64 * 4);
    int*   eflag    = (int*)  alloc(256);
    float* W12f     = (float*)alloc(512 * 64 * 4);
    u16*   Bt       = (u16*)  alloc(512 * 64 * 2);
    float* c1       = (float*)alloc(64 * 4);
    int*   csr      = (int*)  alloc((size_t)N_EDGES * 4);
    u16*   z        = (u16*)  alloc((size_t)N_NODES * 64 * 2);
    u16*   y        = (u16*)  alloc((size_t)N_NODES * 64 * 2);
    (void)ws_size;

    hipMemsetAsync(deg, 0, N_NODES * 4, stream);
    hipMemsetAsync(cursor, 0, N_NODES * 4, stream);

    const int EB = (N_EDGES + 255) / 256;
    const int NB = (N_NODES + 255) / 256;
    const int SCAN_BLKS = (N_NODES + 2047) / 2048;   // 49

    k_detect<<<1, 64, 0, stream>>>(ei, eflag);
    k_degree<<<EB, 256, 0, stream>>>(ei, eflag, deg);
    k_scan_part<<<SCAN_BLKS, 256, 0, stream>>>(deg, rowstart, bsums);
    k_scan_sums<<<1, 64, 0, stream>>>(bsums, boffs, SCAN_BLKS);
    k_scan_add_dinv<<<NB, 256, 0, stream>>>(rowstart, boffs, deg, dinv);
    k_fill<<<EB, 256, 0, stream>>>(ei, eflag, rowstart, cursor, csr);

    k_w12<<<128, 256, 0, stream>>>(W1, W2, W12f);
    k_c1<<<1, 64, 0, stream>>>(b1, W2, c1);
    k_fragB<<<16, 256, 0, stream>>>(W12f, Bt);

    gemm_x<<<(N_NODES + 127) / 128, 256, 0, stream>>>(x, Bt, z, N_NODES);
    agg_a<<<N_NODES / 4, 256, 0, stream>>>(z, dinv, rowstart, csr, y);
    agg_b<<<N_NODES / 4, 256, 0, stream>>>(y, dinv, rowstart, csr, c1, b2, out);
}

// Round 4
// 615.464 us; speedup vs baseline: 1.3587x; 1.1552x over previous
//
#include <hip/hip_runtime.h>
#include <hip/hip_bf16.h>

typedef unsigned short u16;
typedef unsigned int   u32;

#define N_NODES 100000
#define N_EDGES 1600000

__device__ __forceinline__ float bf2f(u16 u) {
    union { u32 i; float f; } c; c.i = ((u32)u) << 16; return c.f;
}
__device__ __forceinline__ u16 f2bf(float f) {
    union { float f; u32 i; } c; c.f = f;
    u32 u = c.i;
    u += 0x7fffu + ((u >> 16) & 1u);   // RNE
    return (u16)(u >> 16);
}
__device__ __forceinline__ void acc4(uint2 d, float& a0, float& a1, float& a2, float& a3) {
    a0 += bf2f((u16)(d.x & 0xffffu));
    a1 += bf2f((u16)(d.x >> 16));
    a2 += bf2f((u16)(d.y & 0xffffu));
    a3 += bf2f((u16)(d.y >> 16));
}

// ---------------- edge dtype probe (int32 vs int64 layout) ----------------
__global__ void k_detect(const u32* __restrict__ ei, int* __restrict__ flag) {
    if (threadIdx.x == 0 && blockIdx.x == 0) {
        u32 h = ei[1] | ei[3] | ei[5] | ei[7];
        *flag = (h == 0u) ? 1 : 0;
    }
}
__device__ __forceinline__ int edge_at(const u32* ei, int f, long pos) {
    return f ? (int)ei[2 * pos] : (int)ei[pos];
}

// ---------------- degree / CSR build ----------------

__global__ void k_degree(const u32* __restrict__ ei, const int* __restrict__ flag,
                         int* __restrict__ deg) {
    int e4 = blockIdx.x * 256 + threadIdx.x;
    int f = *flag;
    long e = 4L * e4;
    if (e + 3 < N_EDGES) {
        int d0, d1, d2, d3;
        if (f) {
            uint4 a = *(const uint4*)&ei[2 * ((long)N_EDGES + e)];
            uint4 b = *(const uint4*)&ei[2 * ((long)N_EDGES + e) + 4];
            d0 = (int)a.x; d1 = (int)a.z; d2 = (int)b.x; d3 = (int)b.z;
        } else {
            uint4 a = *(const uint4*)&ei[(long)N_EDGES + e];
            d0 = (int)a.x; d1 = (int)a.y; d2 = (int)a.z; d3 = (int)a.w;
        }
        atomicAdd(&deg[d0], 1); atomicAdd(&deg[d1], 1);
        atomicAdd(&deg[d2], 1); atomicAdd(&deg[d3], 1);
    } else {
        for (; e < N_EDGES; e++) atomicAdd(&deg[edge_at(ei, f, (long)N_EDGES + e)], 1);
    }
}

__global__ void k_scan_part(const int* __restrict__ deg, int* __restrict__ rowstart,
                            int* __restrict__ bsums) {
    __shared__ int sh[256];
    const int t = threadIdx.x, b = blockIdx.x;
    const int base = b * 2048 + t * 8;
    int v[8]; int s = 0;
#pragma unroll
    for (int i = 0; i < 8; i++) {
        int idx = base + i;
        v[i] = (idx < N_NODES) ? deg[idx] : 0;
        s += v[i];
    }
    sh[t] = s;
    __syncthreads();
    for (int d = 1; d < 256; d <<= 1) {
        int x = (t >= d) ? sh[t - d] : 0;
        __syncthreads();
        sh[t] += x;
        __syncthreads();
    }
    int acc = sh[t] - s;
#pragma unroll
    for (int i = 0; i < 8; i++) {
        int idx = base + i;
        if (idx < N_NODES) rowstart[idx] = acc;
        acc += v[i];
    }
    if (t == 255) bsums[b] = sh[255];
}

__global__ void k_scan_sums(const int* __restrict__ bsums, int* __restrict__ boffs, int nb) {
    if (threadIdx.x == 0 && blockIdx.x == 0) {
        int r = 0;
        for (int i = 0; i < nb; i++) { boffs[i] = r; r += bsums[i]; }
    }
}

// rowstart += block offset; cursor = rowstart (so k_fill needs no rowstart read);
// dinv = 1/sqrt(deg+1)
__global__ void k_scan_add_dinv(int* __restrict__ rowstart, const int* __restrict__ boffs,
                                const int* __restrict__ deg, float* __restrict__ dinv,
                                int* __restrict__ cursor) {
    int i = blockIdx.x * blockDim.x + threadIdx.x;
    if (i < N_NODES) {
        int r = rowstart[i] + boffs[i >> 11];
        rowstart[i] = r;
        cursor[i] = r;
        dinv[i] = rsqrtf((float)(deg[i] + 1));
    }
    if (i == 0) rowstart[N_NODES] = N_EDGES;
}

__global__ void k_fill(const u32* __restrict__ ei, const int* __restrict__ flag,
                       int* __restrict__ cursor, int* __restrict__ csr) {
    int e4 = blockIdx.x * 256 + threadIdx.x;
    int f = *flag;
    long e = 4L * e4;
    if (e + 3 < N_EDGES) {
        int s0, s1, s2, s3, d0, d1, d2, d3;
        if (f) {
            uint4 a = *(const uint4*)&ei[2 * e];
            uint4 b = *(const uint4*)&ei[2 * e + 4];
            s0 = (int)a.x; s1 = (int)a.z; s2 = (int)b.x; s3 = (int)b.z;
            uint4 c = *(const uint4*)&ei[2 * ((long)N_EDGES + e)];
            uint4 d = *(const uint4*)&ei[2 * ((long)N_EDGES + e) + 4];
            d0 = (int)c.x; d1 = (int)c.z; d2 = (int)d.x; d3 = (int)d.z;
        } else {
            uint4 a = *(const uint4*)&ei[e];
            s0 = (int)a.x; s1 = (int)a.y; s2 = (int)a.z; s3 = (int)a.w;
            uint4 c = *(const uint4*)&ei[(long)N_EDGES + e];
            d0 = (int)c.x; d1 = (int)c.y; d2 = (int)c.z; d3 = (int)c.w;
        }
        csr[atomicAdd(&cursor[d0], 1)] = s0;
        csr[atomicAdd(&cursor[d1], 1)] = s1;
        csr[atomicAdd(&cursor[d2], 1)] = s2;
        csr[atomicAdd(&cursor[d3], 1)] = s3;
    } else {
        for (; e < N_EDGES; e++) {
            int s = edge_at(ei, f, e);
            int d = edge_at(ei, f, (long)N_EDGES + e);
            csr[atomicAdd(&cursor[d], 1)] = s;
        }
    }
}

// ---------------- weight precompute: W12 = W1@W2 (f32), c1 = b1@W2 ----------------

__global__ void k_w12(const float* __restrict__ W1, const float* __restrict__ W2,
                      float* __restrict__ W12f) {
    int idx = blockIdx.x * 256 + threadIdx.x;   // 512*64
    int k = idx >> 6, n = idx & 63;
    float acc = 0.f;
#pragma unroll 4
    for (int j = 0; j < 128; j++) acc += W1[k * 128 + j] * W2[j * 64 + n];
    W12f[idx] = acc;
}

__global__ void k_c1(const float* __restrict__ b1, const float* __restrict__ W2,
                     float* __restrict__ c1) {
    int n = threadIdx.x;   // 64
    float acc = 0.f;
    for (int j = 0; j < 128; j++) acc += b1[j] * W2[j * 64 + n];
    c1[n] = acc;
}

// fragment-ordered bf16 pack for MFMA B operand
__global__ void k_fragB(const float* __restrict__ W12f, u16* __restrict__ Bt) {
    int idx = blockIdx.x * 256 + threadIdx.x;   // 4096 threads
    int l = idx & 63, c = (idx >> 6) & 3, kt = idx >> 8;
    int n = c * 16 + (l & 15);
    int k0 = kt * 32 + (l >> 4) * 8;
    u32 p[4];
#pragma unroll
    for (int j = 0; j < 4; j++) {
        u16 a = f2bf(W12f[(k0 + 2 * j) * 64 + n]);
        u16 b = f2bf(W12f[(k0 + 2 * j + 1) * 64 + n]);
        p[j] = (u32)a | ((u32)b << 16);
    }
    *(uint4*)&Bt[(long)idx * 8] = make_uint4(p[0], p[1], p[2], p[3]);
}

// ---------------- GEMM: z'[M,64] = (bf16(x) @ Bt) * dinv[row], out bf16 ----------------

__global__ __launch_bounds__(256) void gemm_x(const float* __restrict__ A,
                                              const u16* __restrict__ Bt,
                                              const float* __restrict__ dinv,
                                              u16* __restrict__ C, int M) {
    constexpr int SA = 40;
    __shared__ u16 As[128 * SA];
    typedef __attribute__((ext_vector_type(8))) short v8s;
    typedef __attribute__((ext_vector_type(4))) float v4f;

    const int t = threadIdx.x;
    const int wave = t >> 6, lane = t & 63;
    const int m = lane & 15, quad = lane >> 4;
    const int row0 = blockIdx.x * 128;

    v4f acc[2][4];
#pragma unroll
    for (int i = 0; i < 2; i++)
#pragma unroll
        for (int c = 0; c < 4; c++)
#pragma unroll
            for (int r = 0; r < 4; r++) acc[i][c][r] = 0.0f;

    const int arow = t >> 1, ahalf = t & 1;
    const long aoff = (long)(row0 + arow) * 512;
    const bool arow_ok = (row0 + arow) < M;

    for (int kt = 0; kt < 16; ++kt) {
        const int kk0 = kt * 32 + ahalf * 16;
        float4 f0 = make_float4(0.f, 0.f, 0.f, 0.f), f1 = f0, f2 = f0, f3 = f0;
        if (arow_ok) {
            f0 = *(const float4*)&A[aoff + kk0];
            f1 = *(const float4*)&A[aoff + kk0 + 4];
            f2 = *(const float4*)&A[aoff + kk0 + 8];
            f3 = *(const float4*)&A[aoff + kk0 + 12];
        }
        uint4 w0, w1;
        w0.x = (u32)f2bf(f0.x) | ((u32)f2bf(f0.y) << 16);
        w0.y = (u32)f2bf(f0.z) | ((u32)f2bf(f0.w) << 16);
        w0.z = (u32)f2bf(f1.x) | ((u32)f2bf(f1.y) << 16);
        w0.w = (u32)f2bf(f1.z) | ((u32)f2bf(f1.w) << 16);
        w1.x = (u32)f2bf(f2.x) | ((u32)f2bf(f2.y) << 16);
        w1.y = (u32)f2bf(f2.z) | ((u32)f2bf(f2.w) << 16);
        w1.z = (u32)f2bf(f3.x) | ((u32)f2bf(f3.y) << 16);
        w1.w = (u32)f2bf(f3.z) | ((u32)f2bf(f3.w) << 16);
        *(uint4*)&As[arow * SA + ahalf * 16] = w0;
        *(uint4*)&As[arow * SA + ahalf * 16 + 8] = w1;
        __syncthreads();
        v8s a0 = *(const v8s*)&As[(wave * 32 + m) * SA + quad * 8];
        v8s a1 = *(const v8s*)&As[(wave * 32 + 16 + m) * SA + quad * 8];
#pragma unroll
        for (int c = 0; c < 4; c++) {
            v8s b = *(const v8s*)&Bt[(long)((kt * 4 + c) * 64 + lane) * 8];
            acc[0][c] = __builtin_amdgcn_mfma_f32_16x16x32_bf16(a0, b, acc[0][c], 0, 0, 0);
            acc[1][c] = __builtin_amdgcn_mfma_f32_16x16x32_bf16(a1, b, acc[1][c], 0, 0, 0);
        }
        __syncthreads();
    }
    // D layout: col = lane&15, row = quad*4 + r
#pragma unroll
    for (int i = 0; i < 2; i++)
#pragma unroll
        for (int r = 0; r < 4; r++) {
            int grow = row0 + wave * 32 + i * 16 + quad * 4 + r;
            if (grow < M) {
                float w = dinv[grow];
#pragma unroll
                for (int c = 0; c < 4; c++)
                    C[(long)grow * 64 + c * 16 + m] = f2bf(acc[i][c][r] * w);
            }
        }
}

// ---------------- aggregation pass A ----------------
// T[n] = z'[n] + sum z'[csr]; y'[n] = dinv[n]^2 * T[n] (bf16)
// sfac[n] = dinv[n] * (dinv[n] + sum dinv[csr])  (= row-sum of A_hat)
// Wave = 4 groups of 16 lanes; each group gathers one 128B row per step, 2x unrolled.

__global__ __launch_bounds__(256) void agg_a(const u16* __restrict__ zp,
                                             const float* __restrict__ dinv,
                                             const int* __restrict__ rowstart,
                                             const int* __restrict__ csr,
                                             u16* __restrict__ yp,
                                             float* __restrict__ sfac) {
    const int wave = threadIdx.x >> 6, lane = threadIdx.x & 63;
    const int n = blockIdx.x * 4 + wave;
    const int g = lane >> 4, l = lane & 15;
    const uint2* z2 = (const uint2*)zp;
    float a0 = 0.f, a1 = 0.f, a2 = 0.f, a3 = 0.f, sd = 0.f;
    const float w0 = dinv[n];
    if (g == 0) {
        uint2 d = z2[(long)n * 16 + l];
        acc4(d, a0, a1, a2, a3);
        sd = w0;
    }
    const int i1 = rowstart[n + 1];
    int i = rowstart[n] + g;
    for (; i + 4 < i1; i += 8) {
        int s0 = csr[i], s1 = csr[i + 4];
        uint2 d0 = z2[(long)s0 * 16 + l];
        uint2 d1 = z2[(long)s1 * 16 + l];
        sd += dinv[s0] + dinv[s1];
        acc4(d0, a0, a1, a2, a3);
        acc4(d1, a0, a1, a2, a3);
    }
    if (i < i1) {
        int s = csr[i];
        uint2 d = z2[(long)s * 16 + l];
        sd += dinv[s];
        acc4(d, a0, a1, a2, a3);
    }
    a0 += __shfl_xor(a0, 16); a0 += __shfl_xor(a0, 32);
    a1 += __shfl_xor(a1, 16); a1 += __shfl_xor(a1, 32);
    a2 += __shfl_xor(a2, 16); a2 += __shfl_xor(a2, 32);
    a3 += __shfl_xor(a3, 16); a3 += __shfl_xor(a3, 32);
    sd += __shfl_xor(sd, 16); sd += __shfl_xor(sd, 32);
    if (g == 0) {
        float w2 = w0 * w0;
        uint2 o;
        o.x = (u32)f2bf(a0 * w2) | ((u32)f2bf(a1 * w2) << 16);
        o.y = (u32)f2bf(a2 * w2) | ((u32)f2bf(a3 * w2) << 16);
        ((uint2*)yp)[(long)n * 16 + l] = o;
        if (l == 0) sfac[n] = w0 * sd;
    }
}

// ---------------- aggregation pass B ----------------
// U[n] = y'[n] + sum y'[csr]; out[n] = relu(dinv[n]*U[n] + sfac[n]*c1 + b2), f32

__global__ __launch_bounds__(256) void agg_b(const u16* __restrict__ yp,
                                             const float* __restrict__ dinv,
                                             const int* __restrict__ rowstart,
                                             const int* __restrict__ csr,
                                             const float* __restrict__ sfac,
                                             const float* __restrict__ c1,
                                             const float* __restrict__ b2,
                                             float* __restrict__ out) {
    const int wave = threadIdx.x >> 6, lane = threadIdx.x & 63;
    const int n = blockIdx.x * 4 + wave;
    const int g = lane >> 4, l = lane & 15;
    const uint2* y2 = (const uint2*)yp;
    float a0 = 0.f, a1 = 0.f, a2 = 0.f, a3 = 0.f;
    if (g == 0) {
        uint2 d = y2[(long)n * 16 + l];
        acc4(d, a0, a1, a2, a3);
    }
    const int i1 = rowstart[n + 1];
    int i = rowstart[n] + g;
    for (; i + 4 < i1; i += 8) {
        int s0 = csr[i], s1 = csr[i + 4];
        uint2 d0 = y2[(long)s0 * 16 + l];
        uint2 d1 = y2[(long)s1 * 16 + l];
        acc4(d0, a0, a1, a2, a3);
        acc4(d1, a0, a1, a2, a3);
    }
    if (i < i1) {
        uint2 d = y2[(long)csr[i] * 16 + l];
        acc4(d, a0, a1, a2, a3);
    }
    a0 += __shfl_xor(a0, 16); a0 += __shfl_xor(a0, 32);
    a1 += __shfl_xor(a1, 16); a1 += __shfl_xor(a1, 32);
    a2 += __shfl_xor(a2, 16); a2 += __shfl_xor(a2, 32);
    a3 += __shfl_xor(a3, 16); a3 += __shfl_xor(a3, 32);
    if (g == 0) {
        const float w0 = dinv[n];
        const float sn = sfac[n];
        float4 cv = ((const float4*)c1)[l];
        float4 bv = ((const float4*)b2)[l];
        float4 r;
        r.x = fmaxf(a0 * w0 + sn * cv.x + bv.x, 0.f);
        r.y = fmaxf(a1 * w0 + sn * cv.y + bv.y, 0.f);
        r.z = fmaxf(a2 * w0 + sn * cv.z + bv.z, 0.f);
        r.w = fmaxf(a3 * w0 + sn * cv.w + bv.w, 0.f);
        ((float4*)out)[(long)n * 16 + l] = r;
    }
}

// ---------------- host launch ----------------

extern "C" void kernel_launch(void* const* d_in, const int* in_sizes, int n_in,
                              void* d_out, int out_size, void* d_ws, size_t ws_size,
                              hipStream_t stream) {
    const float* x  = (const float*)d_in[0];
    const u32*   ei = (const u32*)d_in[1];
    const float* W1 = (const float*)d_in[2];
    const float* b1 = (const float*)d_in[3];
    const float* W2 = (const float*)d_in[4];
    const float* b2 = (const float*)d_in[5];
    float* out = (float*)d_out;

    char* ws = (char*)d_ws;
    size_t o = 0;
    auto alloc = [&](size_t bytes) -> char* {
        char* p = ws + o;
        o = (o + bytes + 255) & ~(size_t)255;
        return p;
    };
    int*   deg      = (int*)  alloc(N_NODES * 4);
    float* dinv     = (float*)alloc(N_NODES * 4);
    int*   rowstart = (int*)  alloc((N_NODES + 1) * 4);
    int*   cursor   = (int*)  alloc(N_NODES * 4);
    int*   bsums    = (int*)  alloc(64 * 4);
    int*   boffs    = (int*)  alloc(64 * 4);
    int*   eflag    = (int*)  alloc(256);
    float* W12f     = (float*)alloc(512 * 64 * 4);
    u16*   Bt       = (u16*)  alloc(512 * 64 * 2);
    float* c1       = (float*)alloc(64 * 4);
    float* sfac     = (float*)alloc(N_NODES * 4);
    int*   csr      = (int*)  alloc((size_t)N_EDGES * 4);
    u16*   z        = (u16*)  alloc((size_t)N_NODES * 64 * 2);
    u16*   y        = (u16*)  alloc((size_t)N_NODES * 64 * 2);
    (void)ws_size;

    hipMemsetAsync(deg, 0, N_NODES * 4, stream);

    const int NB = (N_NODES + 255) / 256;
    const int EB4 = (N_EDGES / 4 + 255) / 256;       // 1563
    const int SCAN_BLKS = (N_NODES + 2047) / 2048;   // 49

    k_detect<<<1, 64, 0, stream>>>(ei, eflag);
    k_degree<<<EB4, 256, 0, stream>>>(ei, eflag, deg);
    k_scan_part<<<SCAN_BLKS, 256, 0, stream>>>(deg, rowstart, bsums);
    k_scan_sums<<<1, 64, 0, stream>>>(bsums, boffs, SCAN_BLKS);
    k_scan_add_dinv<<<NB, 256, 0, stream>>>(rowstart, boffs, deg, dinv, cursor);
    k_fill<<<EB4, 256, 0, stream>>>(ei, eflag, cursor, csr);

    k_w12<<<128, 256, 0, stream>>>(W1, W2, W12f);
    k_c1<<<1, 64, 0, stream>>>(b1, W2, c1);
    k_fragB<<<16, 256, 0, stream>>>(W12f, Bt);

    gemm_x<<<(N_NODES + 127) / 128, 256, 0, stream>>>(x, Bt, dinv, z, N_NODES);
    agg_a<<<N_NODES / 4, 256, 0, stream>>>(z, dinv, rowstart, csr, y, sfac);
    agg_b<<<N_NODES / 4, 256, 0, stream>>>(y, dinv, rowstart, csr, sfac, c1, b2, out);
}

// Round 5
// 571.423 us; speedup vs baseline: 1.4635x; 1.0771x over previous
//
#include <hip/hip_runtime.h>
#include <hip/hip_bf16.h>

typedef unsigned short u16;
typedef unsigned int   u32;

#define N_NODES 100000
#define N_EDGES 1600000
#define NQ      (N_EDGES / 4)     // 400000 uint4 quads per endpoint array
#define SLICE   12500             // N_NODES / 8
#define BPG     96                // blocks per dst-slice group in build kernels

__device__ __forceinline__ float bf2f(u16 u) {
    union { u32 i; float f; } c; c.i = ((u32)u) << 16; return c.f;
}
__device__ __forceinline__ u16 f2bf(float f) {
    union { float f; u32 i; } c; c.f = f;
    u32 u = c.i;
    u += 0x7fffu + ((u >> 16) & 1u);   // RNE
    return (u16)(u >> 16);
}
__device__ __forceinline__ void acc8(uint4 d, float* a) {
    a[0] += bf2f((u16)(d.x & 0xffffu)); a[1] += bf2f((u16)(d.x >> 16));
    a[2] += bf2f((u16)(d.y & 0xffffu)); a[3] += bf2f((u16)(d.y >> 16));
    a[4] += bf2f((u16)(d.z & 0xffffu)); a[5] += bf2f((u16)(d.z >> 16));
    a[6] += bf2f((u16)(d.w & 0xffffu)); a[7] += bf2f((u16)(d.w >> 16));
}

// ---------------- edge dtype probe (int32 vs int64 layout) ----------------
__global__ void k_detect(const u32* __restrict__ ei, int* __restrict__ flag) {
    if (threadIdx.x == 0 && blockIdx.x == 0) {
        u32 h = ei[1] | ei[3] | ei[5] | ei[7];
        *flag = (h == 0u) ? 1 : 0;
    }
}

// ---------------- flatten edge_index to int32 src/dst ----------------
__global__ __launch_bounds__(256) void k_convert(const u32* __restrict__ ei,
                                                 const int* __restrict__ flag,
                                                 uint4* __restrict__ src4,
                                                 uint4* __restrict__ dst4) {
    int q = blockIdx.x * 256 + threadIdx.x;
    if (q >= NQ) return;
    const uint4* e4 = (const uint4*)ei;
    if (*flag) {   // int64: (lo,hi) pairs, hi==0
        uint4 a = e4[2 * q],          b = e4[2 * q + 1];
        src4[q] = make_uint4(a.x, a.z, b.x, b.z);
        uint4 c = e4[2 * NQ + 2 * q], d = e4[2 * NQ + 2 * q + 1];
        dst4[q] = make_uint4(c.x, c.z, d.x, d.z);
    } else {       // int32
        src4[q] = e4[q];
        dst4[q] = e4[NQ + q];
    }
}

// ---------------- degree (dst-slice partitioned; slice = blockIdx&7 ~ XCD) ----------------
__global__ __launch_bounds__(256) void k_degree(const uint4* __restrict__ dst4,
                                                int* __restrict__ deg) {
    const int g = blockIdx.x & 7, bb = blockIdx.x >> 3;
    const int lo = g * SLICE, hi = lo + SLICE;
    for (int q = bb * 256 + threadIdx.x; q < NQ; q += BPG * 256) {
        uint4 d = dst4[q];
        if ((int)d.x >= lo && (int)d.x < hi) atomicAdd(&deg[d.x], 1);
        if ((int)d.y >= lo && (int)d.y < hi) atomicAdd(&deg[d.y], 1);
        if ((int)d.z >= lo && (int)d.z < hi) atomicAdd(&deg[d.z], 1);
        if ((int)d.w >= lo && (int)d.w < hi) atomicAdd(&deg[d.w], 1);
    }
}

// ---------------- exclusive scan over degrees ----------------
__global__ void k_scan_part(const int* __restrict__ deg, int* __restrict__ rowstart,
                            int* __restrict__ bsums) {
    __shared__ int sh[256];
    const int t = threadIdx.x, b = blockIdx.x;
    const int base = b * 2048 + t * 8;
    int v[8]; int s = 0;
#pragma unroll
    for (int i = 0; i < 8; i++) {
        int idx = base + i;
        v[i] = (idx < N_NODES) ? deg[idx] : 0;
        s += v[i];
    }
    sh[t] = s;
    __syncthreads();
    for (int d = 1; d < 256; d <<= 1) {
        int x = (t >= d) ? sh[t - d] : 0;
        __syncthreads();
        sh[t] += x;
        __syncthreads();
    }
    int acc = sh[t] - s;
#pragma unroll
    for (int i = 0; i < 8; i++) {
        int idx = base + i;
        if (idx < N_NODES) rowstart[idx] = acc;
        acc += v[i];
    }
    if (t == 255) bsums[b] = sh[255];
}

__global__ void k_scan_sums(const int* __restrict__ bsums, int* __restrict__ boffs, int nb) {
    if (threadIdx.x == 0 && blockIdx.x == 0) {
        int r = 0;
        for (int i = 0; i < nb; i++) { boffs[i] = r; r += bsums[i]; }
    }
}

__global__ void k_scan_add_dinv(int* __restrict__ rowstart, const int* __restrict__ boffs,
                                const int* __restrict__ deg, float* __restrict__ dinv,
                                int* __restrict__ cursor) {
    int i = blockIdx.x * blockDim.x + threadIdx.x;
    if (i < N_NODES) {
        int r = rowstart[i] + boffs[i >> 11];
        rowstart[i] = r;
        cursor[i] = r;
        dinv[i] = rsqrtf((float)(deg[i] + 1));
    }
    if (i == 0) rowstart[N_NODES] = N_EDGES;
}

// ---------------- CSR fill (dst-slice partitioned) ----------------
__global__ __launch_bounds__(256) void k_fill(const uint4* __restrict__ dst4,
                                              const int* __restrict__ src32,
                                              int* __restrict__ cursor,
                                              int* __restrict__ csr) {
    const int g = blockIdx.x & 7, bb = blockIdx.x >> 3;
    const int lo = g * SLICE, hi = lo + SLICE;
    for (int q = bb * 256 + threadIdx.x; q < NQ; q += BPG * 256) {
        uint4 d = dst4[q];
        if ((int)d.x >= lo && (int)d.x < hi) csr[atomicAdd(&cursor[d.x], 1)] = src32[4 * q];
        if ((int)d.y >= lo && (int)d.y < hi) csr[atomicAdd(&cursor[d.y], 1)] = src32[4 * q + 1];
        if ((int)d.z >= lo && (int)d.z < hi) csr[atomicAdd(&cursor[d.z], 1)] = src32[4 * q + 2];
        if ((int)d.w >= lo && (int)d.w < hi) csr[atomicAdd(&cursor[d.w], 1)] = src32[4 * q + 3];
    }
}

// ---------------- weight precompute: W12 = W1@W2 (f32), c1 = b1@W2 ----------------

__global__ void k_w12(const float* __restrict__ W1, const float* __restrict__ W2,
                      float* __restrict__ W12f) {
    int idx = blockIdx.x * 256 + threadIdx.x;   // 512*64
    int k = idx >> 6, n = idx & 63;
    float acc = 0.f;
#pragma unroll 4
    for (int j = 0; j < 128; j++) acc += W1[k * 128 + j] * W2[j * 64 + n];
    W12f[idx] = acc;
}

__global__ void k_c1(const float* __restrict__ b1, const float* __restrict__ W2,
                     float* __restrict__ c1) {
    int n = threadIdx.x;   // 64
    float acc = 0.f;
    for (int j = 0; j < 128; j++) acc += b1[j] * W2[j * 64 + n];
    c1[n] = acc;
}

// fragment-ordered bf16 pack for MFMA B operand
__global__ void k_fragB(const float* __restrict__ W12f, u16* __restrict__ Bt) {
    int idx = blockIdx.x * 256 + threadIdx.x;   // 4096 threads
    int l = idx & 63, c = (idx >> 6) & 3, kt = idx >> 8;
    int n = c * 16 + (l & 15);
    int k0 = kt * 32 + (l >> 4) * 8;
    u32 p[4];
#pragma unroll
    for (int j = 0; j < 4; j++) {
        u16 a = f2bf(W12f[(k0 + 2 * j) * 64 + n]);
        u16 b = f2bf(W12f[(k0 + 2 * j + 1) * 64 + n]);
        p[j] = (u32)a | ((u32)b << 16);
    }
    *(uint4*)&Bt[(long)idx * 8] = make_uint4(p[0], p[1], p[2], p[3]);
}

// ---------------- GEMM: z'[M,64] = (bf16(x) @ Bt) * dinv[row], out bf16 ----------------

__global__ __launch_bounds__(256) void gemm_x(const float* __restrict__ A,
                                              const u16* __restrict__ Bt,
                                              const float* __restrict__ dinv,
                                              u16* __restrict__ C, int M) {
    constexpr int SA = 40;
    __shared__ u16 As[128 * SA];
    typedef __attribute__((ext_vector_type(8))) short v8s;
    typedef __attribute__((ext_vector_type(4))) float v4f;

    const int t = threadIdx.x;
    const int wave = t >> 6, lane = t & 63;
    const int m = lane & 15, quad = lane >> 4;
    const int row0 = blockIdx.x * 128;

    v4f acc[2][4];
#pragma unroll
    for (int i = 0; i < 2; i++)
#pragma unroll
        for (int c = 0; c < 4; c++)
#pragma unroll
            for (int r = 0; r < 4; r++) acc[i][c][r] = 0.0f;

    const int arow = t >> 1, ahalf = t & 1;
    const long aoff = (long)(row0 + arow) * 512;
    const bool arow_ok = (row0 + arow) < M;

    for (int kt = 0; kt < 16; ++kt) {
        const int kk0 = kt * 32 + ahalf * 16;
        float4 f0 = make_float4(0.f, 0.f, 0.f, 0.f), f1 = f0, f2 = f0, f3 = f0;
        if (arow_ok) {
            f0 = *(const float4*)&A[aoff + kk0];
            f1 = *(const float4*)&A[aoff + kk0 + 4];
            f2 = *(const float4*)&A[aoff + kk0 + 8];
            f3 = *(const float4*)&A[aoff + kk0 + 12];
        }
        uint4 w0, w1;
        w0.x = (u32)f2bf(f0.x) | ((u32)f2bf(f0.y) << 16);
        w0.y = (u32)f2bf(f0.z) | ((u32)f2bf(f0.w) << 16);
        w0.z = (u32)f2bf(f1.x) | ((u32)f2bf(f1.y) << 16);
        w0.w = (u32)f2bf(f1.z) | ((u32)f2bf(f1.w) << 16);
        w1.x = (u32)f2bf(f2.x) | ((u32)f2bf(f2.y) << 16);
        w1.y = (u32)f2bf(f2.z) | ((u32)f2bf(f2.w) << 16);
        w1.z = (u32)f2bf(f3.x) | ((u32)f2bf(f3.y) << 16);
        w1.w = (u32)f2bf(f3.z) | ((u32)f2bf(f3.w) << 16);
        *(uint4*)&As[arow * SA + ahalf * 16] = w0;
        *(uint4*)&As[arow * SA + ahalf * 16 + 8] = w1;
        __syncthreads();
        v8s a0 = *(const v8s*)&As[(wave * 32 + m) * SA + quad * 8];
        v8s a1 = *(const v8s*)&As[(wave * 32 + 16 + m) * SA + quad * 8];
#pragma unroll
        for (int c = 0; c < 4; c++) {
            v8s b = *(const v8s*)&Bt[(long)((kt * 4 + c) * 64 + lane) * 8];
            acc[0][c] = __builtin_amdgcn_mfma_f32_16x16x32_bf16(a0, b, acc[0][c], 0, 0, 0);
            acc[1][c] = __builtin_amdgcn_mfma_f32_16x16x32_bf16(a1, b, acc[1][c], 0, 0, 0);
        }
        __syncthreads();
    }
    // D layout: col = lane&15, row = quad*4 + r
#pragma unroll
    for (int i = 0; i < 2; i++)
#pragma unroll
        for (int r = 0; r < 4; r++) {
            int grow = row0 + wave * 32 + i * 16 + quad * 4 + r;
            if (grow < M) {
                float w = dinv[grow];
#pragma unroll
                for (int c = 0; c < 4; c++)
                    C[(long)grow * 64 + c * 16 + m] = f2bf(acc[i][c][r] * w);
            }
        }
}

// ---------------- aggregation pass A ----------------
// 8 groups x 8 lanes; each group gathers one 128B row (uint4/lane) per step, 2x unrolled.
// y'[n] = dinv[n]^2 * (z'[n] + sum z'[csr]); sfac[n] = dinv[n]*(dinv[n] + sum dinv[csr])

__global__ __launch_bounds__(256) void agg_a(const u16* __restrict__ zp,
                                             const float* __restrict__ dinv,
                                             const int* __restrict__ rowstart,
                                             const int* __restrict__ csr,
                                             u16* __restrict__ yp,
                                             float* __restrict__ sfac) {
    const int wave = threadIdx.x >> 6, lane = threadIdx.x & 63;
    const int n = blockIdx.x * 4 + wave;
    const int g = lane >> 3, l = lane & 7;
    const uint4* z4 = (const uint4*)zp;
    float a[8] = {0.f, 0.f, 0.f, 0.f, 0.f, 0.f, 0.f, 0.f};
    float sd = 0.f;
    const float w0 = dinv[n];
    if (g == 0) {
        acc8(z4[(long)n * 8 + l], a);
        sd = w0;
    }
    const int i1 = rowstart[n + 1];
    int i = rowstart[n] + g;
    for (; i + 8 < i1; i += 16) {
        int s0 = csr[i], s1 = csr[i + 8];
        uint4 d0 = z4[(long)s0 * 8 + l];
        uint4 d1 = z4[(long)s1 * 8 + l];
        sd += dinv[s0] + dinv[s1];
        acc8(d0, a); acc8(d1, a);
    }
    for (; i < i1; i += 8) {
        int s = csr[i];
        uint4 d = z4[(long)s * 8 + l];
        sd += dinv[s];
        acc8(d, a);
    }
#pragma unroll
    for (int j = 0; j < 8; j++) {
        a[j] += __shfl_xor(a[j], 8);
        a[j] += __shfl_xor(a[j], 16);
        a[j] += __shfl_xor(a[j], 32);
    }
    sd += __shfl_xor(sd, 8); sd += __shfl_xor(sd, 16); sd += __shfl_xor(sd, 32);
    if (g == 0) {
        float w2 = w0 * w0;
        uint4 o;
        o.x = (u32)f2bf(a[0] * w2) | ((u32)f2bf(a[1] * w2) << 16);
        o.y = (u32)f2bf(a[2] * w2) | ((u32)f2bf(a[3] * w2) << 16);
        o.z = (u32)f2bf(a[4] * w2) | ((u32)f2bf(a[5] * w2) << 16);
        o.w = (u32)f2bf(a[6] * w2) | ((u32)f2bf(a[7] * w2) << 16);
        ((uint4*)yp)[(long)n * 8 + l] = o;
        if (l == 0) sfac[n] = w0 * sd;
    }
}

// ---------------- aggregation pass B ----------------
// out[n] = relu(dinv[n]*(y'[n] + sum y'[csr]) + sfac[n]*c1 + b2), f32

__global__ __launch_bounds__(256) void agg_b(const u16* __restrict__ yp,
                                             const float* __restrict__ dinv,
                                             const int* __restrict__ rowstart,
                                             const int* __restrict__ csr,
                                             const float* __restrict__ sfac,
                                             const float* __restrict__ c1,
                                             const float* __restrict__ b2,
                                             float* __restrict__ out) {
    const int wave = threadIdx.x >> 6, lane = threadIdx.x & 63;
    const int n = blockIdx.x * 4 + wave;
    const int g = lane >> 3, l = lane & 7;
    const uint4* y4 = (const uint4*)yp;
    float a[8] = {0.f, 0.f, 0.f, 0.f, 0.f, 0.f, 0.f, 0.f};
    if (g == 0) acc8(y4[(long)n * 8 + l], a);
    const int i1 = rowstart[n + 1];
    int i = rowstart[n] + g;
    for (; i + 8 < i1; i += 16) {
        int s0 = csr[i], s1 = csr[i + 8];
        uint4 d0 = y4[(long)s0 * 8 + l];
        uint4 d1 = y4[(long)s1 * 8 + l];
        acc8(d0, a); acc8(d1, a);
    }
    for (; i < i1; i += 8) {
        uint4 d = y4[(long)csr[i] * 8 + l];
        acc8(d, a);
    }
#pragma unroll
    for (int j = 0; j < 8; j++) {
        a[j] += __shfl_xor(a[j], 8);
        a[j] += __shfl_xor(a[j], 16);
        a[j] += __shfl_xor(a[j], 32);
    }
    if (g == 0) {
        const float w0 = dinv[n];
        const float sn = sfac[n];
        float4 c0 = ((const float4*)c1)[2 * l], c4 = ((const float4*)c1)[2 * l + 1];
        float4 b0 = ((const float4*)b2)[2 * l], b4 = ((const float4*)b2)[2 * l + 1];
        float4 r0, r1;
        r0.x = fmaxf(a[0] * w0 + sn * c0.x + b0.x, 0.f);
        r0.y = fmaxf(a[1] * w0 + sn * c0.y + b0.y, 0.f);
        r0.z = fmaxf(a[2] * w0 + sn * c0.z + b0.z, 0.f);
        r0.w = fmaxf(a[3] * w0 + sn * c0.w + b0.w, 0.f);
        r1.x = fmaxf(a[4] * w0 + sn * c4.x + b4.x, 0.f);
        r1.y = fmaxf(a[5] * w0 + sn * c4.y + b4.y, 0.f);
        r1.z = fmaxf(a[6] * w0 + sn * c4.z + b4.z, 0.f);
        r1.w = fmaxf(a[7] * w0 + sn * c4.w + b4.w, 0.f);
        ((float4*)out)[(long)n * 16 + 2 * l]     = r0;
        ((float4*)out)[(long)n * 16 + 2 * l + 1] = r1;
    }
}

// ---------------- host launch ----------------

extern "C" void kernel_launch(void* const* d_in, const int* in_sizes, int n_in,
                              void* d_out, int out_size, void* d_ws, size_t ws_size,
                              hipStream_t stream) {
    const float* x  = (const float*)d_in[0];
    const u32*   ei = (const u32*)d_in[1];
    const float* W1 = (const float*)d_in[2];
    const float* b1 = (const float*)d_in[3];
    const float* W2 = (const float*)d_in[4];
    const float* b2 = (const float*)d_in[5];
    float* out = (float*)d_out;

    char* ws = (char*)d_ws;
    size_t o = 0;
    auto alloc = [&](size_t bytes) -> char* {
        char* p = ws + o;
        o = (o + bytes + 255) & ~(size_t)255;
        return p;
    };
    int*   deg      = (int*)  alloc(N_NODES * 4);
    float* dinv     = (float*)alloc(N_NODES * 4);
    int*   rowstart = (int*)  alloc((N_NODES + 1) * 4);
    int*   cursor   = (int*)  alloc(N_NODES * 4);
    int*   bsums    = (int*)  alloc(64 * 4);
    int*   boffs    = (int*)  alloc(64 * 4);
    int*   eflag    = (int*)  alloc(256);
    float* W12f     = (float*)alloc(512 * 64 * 4);
    u16*   Bt       = (u16*)  alloc(512 * 64 * 2);
    float* c1       = (float*)alloc(64 * 4);
    float* sfac     = (float*)alloc(N_NODES * 4);
    uint4* src4     = (uint4*)alloc((size_t)N_EDGES * 4);
    uint4* dst4     = (uint4*)alloc((size_t)N_EDGES * 4);
    int*   csr      = (int*)  alloc((size_t)N_EDGES * 4);
    u16*   z        = (u16*)  alloc((size_t)N_NODES * 64 * 2);
    u16*   y        = (u16*)  alloc((size_t)N_NODES * 64 * 2);
    (void)ws_size;

    hipMemsetAsync(deg, 0, N_NODES * 4, stream);

    const int NB = (N_NODES + 255) / 256;
    const int CQ = (NQ + 255) / 256;                 // 1563
    const int SCAN_BLKS = (N_NODES + 2047) / 2048;   // 49

    k_detect<<<1, 64, 0, stream>>>(ei, eflag);
    k_convert<<<CQ, 256, 0, stream>>>(ei, eflag, src4, dst4);
    k_degree<<<8 * BPG, 256, 0, stream>>>(dst4, deg);
    k_scan_part<<<SCAN_BLKS, 256, 0, stream>>>(deg, rowstart, bsums);
    k_scan_sums<<<1, 64, 0, stream>>>(bsums, boffs, SCAN_BLKS);
    k_scan_add_dinv<<<NB, 256, 0, stream>>>(rowstart, boffs, deg, dinv, cursor);
    k_fill<<<8 * BPG, 256, 0, stream>>>(dst4, (const int*)src4, cursor, csr);

    k_w12<<<128, 256, 0, stream>>>(W1, W2, W12f);
    k_c1<<<1, 64, 0, stream>>>(b1, W2, c1);
    k_fragB<<<16, 256, 0, stream>>>(W12f, Bt);

    gemm_x<<<(N_NODES + 127) / 128, 256, 0, stream>>>(x, Bt, dinv, z, N_NODES);
    agg_a<<<N_NODES / 4, 256, 0, stream>>>(z, dinv, rowstart, csr, y, sfac);
    agg_b<<<N_NODES / 4, 256, 0, stream>>>(y, dinv, rowstart, csr, sfac, c1, b2, out);
}